// Round 13
// baseline (45.782 us; speedup 1.0000x reference)
//
#include <hip/hip_runtime.h>
#include <hip/hip_bf16.h>

// mIoU loss, pair-key histogram, SINGLE fused kernel (last-block finalize).
// Ledger:
//  R1: global atomics on 60 addrs -> 313us.
//  R2~R3: DS op mix irrelevant (42us invariant).
//  R4~R6: C-level MLP idioms defeated by allocator (VGPR 28/36/44).
//  R7 ablation: plain-load probe ~27us (~5 TB/s) -> load path is the wall.
//  R8~R11: DMA pipeline experiments; NCOPY<32 adds bank conflicts;
//      inline-asm loads get hidden serializing waits (allocator). Best
//      clean config = R12.
//  R12: NCOPY=32 zero-conflict + NSLOT=4 + BLK=512 (1 blk/CU, 64KB/CU in
//      flight): 30.7us. Depth 2x gave +6.5% -> approaching ~5 TB/s cap
//      (== R7 probe). Consume fully subdominant (~1us DS, hidden).
//  R13: NSLOT=6 (96KB/CU in flight, 149.5KB LDS, still 1 blk/CU) + FUSE
//      the reduce kernel via last-block-done (devscope ctr + threadfence,
//      rocPRIM cross-XCD pattern; 1 atomic/block = 256 total). Saves one
//      graph launch (~2-3us).

#define NB      20
#define NKEY    (NB * NB)   // 400
#define NCOPY   32
#define BLK     512         // 8 waves
#define NSLOT   6           // slot-pairs in flight (12 DMAs outstanding)
#define GRID_H  256         // exactly 1 block/CU
#define PSTRIDE 64          // padded row per block in workspace

// 16B-per-lane DMA: LDS dest = wave-uniform base + lane*16 (m97/m104).
__device__ __forceinline__ void dma16(const void* g, void* l) {
    __builtin_amdgcn_global_load_lds(
        (const __attribute__((address_space(1))) unsigned*)g,
        (__attribute__((address_space(3))) unsigned*)l, 16, 0, 0);
}

__device__ __forceinline__ void process_pix(int p, int t, unsigned* hist_cp) {
    // ONE fire-and-forget LDS atomic per pixel; key = pred*20+targ.
    atomicAdd(&hist_cp[(p * NB + t) * NCOPY], 1u);
}

__device__ __forceinline__ void process_vec(int4 pv, int4 tv, unsigned* hist_cp) {
    process_pix(pv.x, tv.x, hist_cp);
    process_pix(pv.y, tv.y, hist_cp);
    process_pix(pv.z, tv.z, hist_cp);
    process_pix(pv.w, tv.w, hist_cp);
}

__global__ __launch_bounds__(BLK) void miou_fused_kernel(
        const int4* __restrict__ preds, const int4* __restrict__ targs,
        unsigned* __restrict__ partials, unsigned* __restrict__ done_ctr,
        const int* __restrict__ nb_ptr, const int* __restrict__ smooth_ptr,
        float* __restrict__ out, int n4, int full_iters) {
    __shared__ unsigned s_hist[NKEY * NCOPY];   // 51.2 KB, bank = copy
    __shared__ int4 s_p[NSLOT][BLK];            // 48 KB staging
    __shared__ int4 s_t[NSLOT][BLK];            // 48 KB
    __shared__ int s_last;
    const int tid  = threadIdx.x;
    const int wid  = tid >> 6;
    const int lane = tid & 63;

    unsigned* hist_cp = &s_hist[tid & (NCOPY - 1)];
    const int CHUNK = gridDim.x * BLK;
    const int base  = blockIdx.x * BLK + tid;

    // Prologue DMAs FIRST: latency hides behind init + syncthreads.
    if (full_iters >= NSLOT) {
        #pragma unroll
        for (int s = 0; s < NSLOT; ++s) {
            dma16(&preds[base + s * CHUNK], &s_p[s][wid * 64]);
            dma16(&targs[base + s * CHUNK], &s_t[s][wid * 64]);
        }
    }
    for (int k = tid; k < NKEY * NCOPY; k += BLK) s_hist[k] = 0u;
    __syncthreads();

// One pipeline step: wait for slot J's pair, read it, drain LDS reads,
// refill the slot for J+NSLOT, consume.
#define STEP(J, VM) do {                                              \
    const int slot_ = (J) & 7;  /* NSLOT=6 < 8; J%NSLOT via lookup */ \
    const int sl = (slot_ >= NSLOT) ? slot_ - NSLOT : slot_;          \
    (void)sl;                                                         \
    const int slot2_ = (J) % NSLOT;                                   \
    asm volatile("s_waitcnt vmcnt(" #VM ")" ::: "memory");            \
    int4 pv_ = s_p[slot2_][wid * 64 + lane];                          \
    int4 tv_ = s_t[slot2_][wid * 64 + lane];                          \
    asm volatile("s_waitcnt lgkmcnt(0)" ::: "memory");                \
    if ((J) + NSLOT < full_iters) {                                   \
        dma16(&preds[base + ((J) + NSLOT) * CHUNK], &s_p[slot2_][wid * 64]); \
        dma16(&targs[base + ((J) + NSLOT) * CHUNK], &s_t[slot2_][wid * 64]); \
    }                                                                 \
    process_vec(pv_, tv_, hist_cp);                                   \
} while (0)

    if (full_iters >= NSLOT) {   // host guarantees full==0 or >=NSLOT
        int j = 0;
        for (; j < full_iters - (NSLOT - 1); ++j) STEP(j, 10);
        STEP(j, 8); ++j;    // counted drain: 4 pairs left
        STEP(j, 6); ++j;    // 3 pairs
        STEP(j, 4); ++j;    // 2 pairs
        STEP(j, 2); ++j;    // 1 pair
        STEP(j, 0);         // drained
    }
    // Tail (plain loads; covers remainders and tiny shapes).
    for (int i = base + full_iters * CHUNK; i < n4; i += CHUNK) {
        int4 pv = preds[i];
        int4 tv = targs[i];
        process_vec(pv, tv, hist_cp);
    }
#undef STEP
    __syncthreads();

    // Marginals (NCOPY=32): wave w handles classes w, w+8, ... <NB.
    unsigned* dst = &partials[(size_t)blockIdx.x * PSTRIDE];
    for (int c = wid; c < NB; c += (BLK / 64)) {
        unsigned pcs = 0;
        #pragma unroll
        for (int k = 0; k < 640; k += 64) pcs += s_hist[c * 640 + k + lane];

        unsigned tcs = 0;
        {
            const int copy = lane & 31;
            const int p0   = lane >> 5;   // 0 or 1
            #pragma unroll
            for (int p = 0; p < NB; p += 2)
                tcs += s_hist[((p + p0) * NB + c) * NCOPY + copy];
        }
        unsigned ics = (lane < NCOPY) ? s_hist[(c * 21) * NCOPY + lane] : 0u;

        #pragma unroll
        for (int off = 32; off > 0; off >>= 1) {
            pcs += __shfl_xor(pcs, off);
            tcs += __shfl_xor(tcs, off);
            ics += __shfl_xor(ics, off);
        }
        if (lane == 0) {
            dst[c]          = pcs;
            dst[NB + c]     = tcs;
            dst[2 * NB + c] = ics;
        }
    }

    // ---- Last-block finalize (fused reduce; saves a kernel launch). ----
    // __syncthreads drains this block's global stores (vmcnt 0) before the
    // fence + device-scope counter atomic publishes them (rocPRIM pattern).
    __syncthreads();
    if (tid == 0) {
        __threadfence();
        unsigned old = atomicAdd(done_ctr, 1u);
        s_last = (old == gridDim.x - 1u) ? 1 : 0;
    }
    __syncthreads();
    if (s_last) {
        __threadfence();   // acquire side
        const int nblocks = gridDim.x;
        const int col  = tid & 63;
        const int rgrp = tid >> 6;          // 0..7
        unsigned acc = 0;
        for (int r = rgrp; r < nblocks; r += 8)
            acc += partials[(size_t)r * PSTRIDE + col];
        unsigned* red = (unsigned*)s_p;     // reuse staging LDS
        red[rgrp * 64 + col] = acc;
        __syncthreads();
        if (tid < 64) {
            unsigned tot = 0;
            #pragma unroll
            for (int k = 0; k < 8; ++k) tot += red[k * 64 + tid];
            red[512 + tid] = tot;
        }
        __syncthreads();
        if (tid == 0) {
            const int   nb = *nb_ptr;
            const float s  = (float)(*smooth_ptr);
            float acc_iou = 0.0f;
            for (int c = 0; c < nb && c < NB; ++c) {
                float pc    = (float)red[512 + c];
                float tc    = (float)red[512 + NB + c];
                float inter = (float)red[512 + 2 * NB + c];
                float uni   = pc + tc - inter;
                acc_iou += (inter + s) / (uni + s);
            }
            out[0] = 1.0f - acc_iou / (float)nb;
        }
    }
}

extern "C" void kernel_launch(void* const* d_in, const int* in_sizes, int n_in,
                              void* d_out, int out_size, void* d_ws, size_t ws_size,
                              hipStream_t stream) {
    const int4* preds      = (const int4*)d_in[0];
    const int4* targs      = (const int4*)d_in[1];
    const int*  nb_ptr     = (const int*)d_in[2];
    const int*  smooth_ptr = (const int*)d_in[3];
    float*      out        = (float*)d_out;

    int n  = in_sizes[0];
    int n4 = n >> 2;  // 16M pixels, divisible by 4

    unsigned* partials = (unsigned*)d_ws;

    int grid = GRID_H;
    int max_grid = (n4 + BLK - 1) / BLK;
    if (grid > max_grid) grid = max_grid;
    if (grid < 1) grid = 1;
    size_t need_per_block = PSTRIDE * sizeof(unsigned);
    if ((size_t)(grid + 1) * need_per_block > ws_size)
        grid = (int)(ws_size / need_per_block) - 1;

    unsigned* done_ctr = partials + (size_t)grid * PSTRIDE;
    hipMemsetAsync(done_ctr, 0, sizeof(unsigned), stream);

    int chunk = grid * BLK;
    int full  = (chunk > 0) ? (n4 / chunk) : 0;
    if (full < NSLOT) full = 0;   // tiny shapes -> tail path handles all

    miou_fused_kernel<<<grid, BLK, 0, stream>>>(
        preds, targs, partials, done_ctr, nb_ptr, smooth_ptr, out, n4, full);
}

// Round 14
// 44.850 us; speedup vs baseline: 1.0208x; 1.0208x over previous
//
#include <hip/hip_runtime.h>
#include <hip/hip_bf16.h>

// mIoU loss, pair-key histogram, SINGLE fused kernel (last-block finalize).
// Ledger:
//  R1: global atomics on 60 addrs -> 313us.
//  R2~R3: DS op mix irrelevant (42us invariant).
//  R4~R6: C-level MLP idioms defeated by allocator (VGPR 28/36/44).
//  R7 ablation: plain-load probe ~27us (~5 TB/s) -> load path is the wall.
//  R8~R11: DMA pipeline experiments; NCOPY<32 adds bank conflicts;
//      inline-asm loads get hidden serializing waits. Best clean = R12.
//  R12 (BEST, 30.7us): NCOPY=32 zero-conflict + NSLOT=4 + BLK=512,
//      1 blk/CU, 64KB/CU in flight, counted vmcnt 6 steady / 4,2,0 drain.
//  R13 FAILED (45.8us): two changes at once. NSLOT=6 broke the pow2 ring
//      (runtime %6 = magic-mul + unfoldable LDS bases) + 150KB LDS.
//      Fusion itself never isolated.
//  R14: EXACT R12 streaming loop + ONLY the fusion (last-block-done,
//      devscope ctr + threadfence, rocPRIM cross-XCD pattern).

#define NB      20
#define NKEY    (NB * NB)   // 400
#define NCOPY   32
#define BLK     512         // 8 waves
#define NSLOT   4           // slot-pairs in flight (8 DMAs outstanding)
#define GRID_H  256         // exactly 1 block/CU
#define PSTRIDE 64          // padded row per block in workspace

// 16B-per-lane DMA: LDS dest = wave-uniform base + lane*16 (m97/m104).
__device__ __forceinline__ void dma16(const void* g, void* l) {
    __builtin_amdgcn_global_load_lds(
        (const __attribute__((address_space(1))) unsigned*)g,
        (__attribute__((address_space(3))) unsigned*)l, 16, 0, 0);
}

__device__ __forceinline__ void process_pix(int p, int t, unsigned* hist_cp) {
    // ONE fire-and-forget LDS atomic per pixel; key = pred*20+targ.
    atomicAdd(&hist_cp[(p * NB + t) * NCOPY], 1u);
}

__device__ __forceinline__ void process_vec(int4 pv, int4 tv, unsigned* hist_cp) {
    process_pix(pv.x, tv.x, hist_cp);
    process_pix(pv.y, tv.y, hist_cp);
    process_pix(pv.z, tv.z, hist_cp);
    process_pix(pv.w, tv.w, hist_cp);
}

__global__ __launch_bounds__(BLK) void miou_fused_kernel(
        const int4* __restrict__ preds, const int4* __restrict__ targs,
        unsigned* __restrict__ partials, unsigned* __restrict__ done_ctr,
        const int* __restrict__ nb_ptr, const int* __restrict__ smooth_ptr,
        float* __restrict__ out, int n4, int full_iters) {
    __shared__ unsigned s_hist[NKEY * NCOPY];   // 51.2 KB, bank = copy
    __shared__ int4 s_p[NSLOT][BLK];            // 32 KB staging
    __shared__ int4 s_t[NSLOT][BLK];            // 32 KB
    __shared__ int s_last;
    const int tid  = threadIdx.x;
    const int wid  = tid >> 6;
    const int lane = tid & 63;

    unsigned* hist_cp = &s_hist[tid & (NCOPY - 1)];
    const int CHUNK = gridDim.x * BLK;
    const int base  = blockIdx.x * BLK + tid;

    // Prologue DMAs FIRST: latency hides behind init + syncthreads.
    if (full_iters >= NSLOT) {
        #pragma unroll
        for (int s = 0; s < NSLOT; ++s) {
            dma16(&preds[base + s * CHUNK], &s_p[s][wid * 64]);
            dma16(&targs[base + s * CHUNK], &s_t[s][wid * 64]);
        }
    }
    for (int k = tid; k < NKEY * NCOPY; k += BLK) s_hist[k] = 0u;
    __syncthreads();

// One pipeline step (R12-exact): wait for slot J's pair, read it, drain
// LDS reads, refill the slot for J+NSLOT, consume.
#define STEP(J, VM) do {                                              \
    const int slot_ = (J) & (NSLOT - 1);                              \
    asm volatile("s_waitcnt vmcnt(" #VM ")" ::: "memory");            \
    int4 pv_ = s_p[slot_][wid * 64 + lane];                           \
    int4 tv_ = s_t[slot_][wid * 64 + lane];                           \
    asm volatile("s_waitcnt lgkmcnt(0)" ::: "memory");                \
    if ((J) + NSLOT < full_iters) {                                   \
        dma16(&preds[base + ((J) + NSLOT) * CHUNK], &s_p[slot_][wid * 64]); \
        dma16(&targs[base + ((J) + NSLOT) * CHUNK], &s_t[slot_][wid * 64]); \
    }                                                                 \
    process_vec(pv_, tv_, hist_cp);                                   \
} while (0)

    if (full_iters >= NSLOT) {   // host guarantees full==0 or >=NSLOT
        int j = 0;
        for (; j < full_iters - (NSLOT - 1); ++j) STEP(j, 6);
        STEP(j, 4); ++j;    // counted drain: 2 pairs left in flight
        STEP(j, 2); ++j;    // 1 pair left
        STEP(j, 0);         // drained
    }
    // Tail (plain loads; covers remainders and tiny shapes).
    for (int i = base + full_iters * CHUNK; i < n4; i += CHUNK) {
        int4 pv = preds[i];
        int4 tv = targs[i];
        process_vec(pv, tv, hist_cp);
    }
#undef STEP
    __syncthreads();

    // Marginals (NCOPY=32): wave w handles classes w, w+8, ... <NB.
    //  pc[c] = 640 contiguous words at c*640; tc[c] = 32 words per p at
    //  (p*20+c)*32 (bank = copy: clean); ic[c] = 32 words at (c*21)*32.
    unsigned* dst = &partials[(size_t)blockIdx.x * PSTRIDE];
    for (int c = wid; c < NB; c += (BLK / 64)) {
        unsigned pcs = 0;
        #pragma unroll
        for (int k = 0; k < 640; k += 64) pcs += s_hist[c * 640 + k + lane];

        unsigned tcs = 0;
        {
            const int copy = lane & 31;
            const int p0   = lane >> 5;   // 0 or 1
            #pragma unroll
            for (int p = 0; p < NB; p += 2)
                tcs += s_hist[((p + p0) * NB + c) * NCOPY + copy];
        }
        unsigned ics = (lane < NCOPY) ? s_hist[(c * 21) * NCOPY + lane] : 0u;

        #pragma unroll
        for (int off = 32; off > 0; off >>= 1) {
            pcs += __shfl_xor(pcs, off);
            tcs += __shfl_xor(tcs, off);
            ics += __shfl_xor(ics, off);
        }
        if (lane == 0) {
            dst[c]          = pcs;
            dst[NB + c]     = tcs;
            dst[2 * NB + c] = ics;
        }
    }

    // ---- Last-block finalize (fused reduce; saves a kernel launch). ----
    // __syncthreads drains this block's global stores before the fence +
    // device-scope counter atomic publishes them (rocPRIM pattern).
    __syncthreads();
    if (tid == 0) {
        __threadfence();
        unsigned old = atomicAdd(done_ctr, 1u);
        s_last = (old == gridDim.x - 1u) ? 1 : 0;
    }
    __syncthreads();
    if (s_last) {
        __threadfence();   // acquire side
        const int nblocks = gridDim.x;
        const int col  = tid & 63;
        const int rgrp = tid >> 6;          // 0..7
        unsigned acc = 0;
        for (int r = rgrp; r < nblocks; r += 8)
            acc += partials[(size_t)r * PSTRIDE + col];
        unsigned* red = (unsigned*)s_p;     // reuse staging LDS
        red[rgrp * 64 + col] = acc;
        __syncthreads();
        if (tid < 64) {
            unsigned tot = 0;
            #pragma unroll
            for (int k = 0; k < 8; ++k) tot += red[k * 64 + tid];
            red[512 + tid] = tot;
        }
        __syncthreads();
        if (tid == 0) {
            const int   nb = *nb_ptr;
            const float s  = (float)(*smooth_ptr);
            float acc_iou = 0.0f;
            for (int c = 0; c < nb && c < NB; ++c) {
                float pc    = (float)red[512 + c];
                float tc    = (float)red[512 + NB + c];
                float inter = (float)red[512 + 2 * NB + c];
                float uni   = pc + tc - inter;
                acc_iou += (inter + s) / (uni + s);
            }
            out[0] = 1.0f - acc_iou / (float)nb;
        }
    }
}

extern "C" void kernel_launch(void* const* d_in, const int* in_sizes, int n_in,
                              void* d_out, int out_size, void* d_ws, size_t ws_size,
                              hipStream_t stream) {
    const int4* preds      = (const int4*)d_in[0];
    const int4* targs      = (const int4*)d_in[1];
    const int*  nb_ptr     = (const int*)d_in[2];
    const int*  smooth_ptr = (const int*)d_in[3];
    float*      out        = (float*)d_out;

    int n  = in_sizes[0];
    int n4 = n >> 2;  // 16M pixels, divisible by 4

    unsigned* partials = (unsigned*)d_ws;

    int grid = GRID_H;
    int max_grid = (n4 + BLK - 1) / BLK;
    if (grid > max_grid) grid = max_grid;
    if (grid < 1) grid = 1;
    size_t need_per_block = PSTRIDE * sizeof(unsigned);
    if ((size_t)(grid + 1) * need_per_block > ws_size)
        grid = (int)(ws_size / need_per_block) - 1;

    unsigned* done_ctr = partials + (size_t)grid * PSTRIDE;
    hipMemsetAsync(done_ctr, 0, sizeof(unsigned), stream);

    int chunk = grid * BLK;
    int full  = (chunk > 0) ? (n4 / chunk) : 0;
    if (full < NSLOT) full = 0;   // tiny shapes -> tail path handles all

    miou_fused_kernel<<<grid, BLK, 0, stream>>>(
        preds, targs, partials, done_ctr, nb_ptr, smooth_ptr, out, n4, full);
}

// Round 15
// 31.002 us; speedup vs baseline: 1.4767x; 1.4466x over previous
//
#include <hip/hip_runtime.h>
#include <hip/hip_bf16.h>

// mIoU loss, pair-key histogram, two-stage (no global atomics).
// FINAL CONFIGURATION (= R12, the verified optimum at 30.7us).
// Ledger:
//  R1: global atomics on 60 addrs -> 313us.
//  R2~R3: DS op mix irrelevant (42us invariant).
//  R4~R6: C-level MLP idioms defeated by allocator (VGPR 28/36/44).
//  R7 ablation: plain-load probe ~27us (~5 TB/s) -> load path is the wall.
//  R8~R11: DMA pipeline experiments; NCOPY<32 adds bank conflicts;
//      inline-asm loads get hidden serializing waits.
//  R12 (BEST, 30.7us): NCOPY=32 zero-conflict + NSLOT=4 + BLK=512,
//      1 blk/CU, 64KB/CU in flight, counted vmcnt 6 steady / 4,2,0 drain.
//  R13 (45.8us): NSLOT=6 broke pow2 ring + 150KB LDS. Rejected.
//  R14 (44.8us): last-block fusion isolated -> device-scope threadfence
//      (L2 wb/inv per block) poisons the streaming pipeline. Rejected.
//  R15: exact revert to R12. Every lever independently exhausted at an
//      effective ~4.8-5 TB/s stream, all pipes <20% busy.

#define NB      20
#define NKEY    (NB * NB)   // 400
#define NCOPY   32
#define BLK     512         // 8 waves
#define NSLOT   4           // slot-pairs in flight
#define GRID_H  256         // exactly 1 block/CU
#define PSTRIDE 64          // padded row per block in workspace

// 16B-per-lane DMA: LDS dest = wave-uniform base + lane*16 (m97/m104).
__device__ __forceinline__ void dma16(const void* g, void* l) {
    __builtin_amdgcn_global_load_lds(
        (const __attribute__((address_space(1))) unsigned*)g,
        (__attribute__((address_space(3))) unsigned*)l, 16, 0, 0);
}

__device__ __forceinline__ void process_pix(int p, int t, unsigned* hist_cp) {
    // ONE fire-and-forget LDS atomic per pixel; key = pred*20+targ.
    atomicAdd(&hist_cp[(p * NB + t) * NCOPY], 1u);
}

__device__ __forceinline__ void process_vec(int4 pv, int4 tv, unsigned* hist_cp) {
    process_pix(pv.x, tv.x, hist_cp);
    process_pix(pv.y, tv.y, hist_cp);
    process_pix(pv.z, tv.z, hist_cp);
    process_pix(pv.w, tv.w, hist_cp);
}

__global__ __launch_bounds__(BLK) void miou_hist_kernel(
        const int4* __restrict__ preds, const int4* __restrict__ targs,
        unsigned* __restrict__ partials, int n4, int full_iters) {
    __shared__ unsigned s_hist[NKEY * NCOPY];   // 51.2 KB, bank = copy
    __shared__ int4 s_p[NSLOT][BLK];            // 32 KB staging
    __shared__ int4 s_t[NSLOT][BLK];            // 32 KB
    const int tid  = threadIdx.x;
    const int wid  = tid >> 6;
    const int lane = tid & 63;

    unsigned* hist_cp = &s_hist[tid & (NCOPY - 1)];
    const int CHUNK = gridDim.x * BLK;
    const int base  = blockIdx.x * BLK + tid;

    // Prologue DMAs FIRST: their latency hides behind init + syncthreads.
    if (full_iters >= NSLOT) {
        #pragma unroll
        for (int s = 0; s < NSLOT; ++s) {
            dma16(&preds[base + s * CHUNK], &s_p[s][wid * 64]);
            dma16(&targs[base + s * CHUNK], &s_t[s][wid * 64]);
        }
    }
    for (int k = tid; k < NKEY * NCOPY; k += BLK) s_hist[k] = 0u;
    __syncthreads();

// One pipeline step: wait for slot J's pair, read it, drain LDS reads,
// refill the slot for J+NSLOT, consume.
#define STEP(J, VM) do {                                              \
    const int slot_ = (J) & (NSLOT - 1);                              \
    asm volatile("s_waitcnt vmcnt(" #VM ")" ::: "memory");            \
    int4 pv_ = s_p[slot_][wid * 64 + lane];                           \
    int4 tv_ = s_t[slot_][wid * 64 + lane];                           \
    asm volatile("s_waitcnt lgkmcnt(0)" ::: "memory");                \
    if ((J) + NSLOT < full_iters) {                                   \
        dma16(&preds[base + ((J) + NSLOT) * CHUNK], &s_p[slot_][wid * 64]); \
        dma16(&targs[base + ((J) + NSLOT) * CHUNK], &s_t[slot_][wid * 64]); \
    }                                                                 \
    process_vec(pv_, tv_, hist_cp);                                   \
} while (0)

    if (full_iters >= NSLOT) {   // host guarantees full==0 or >=NSLOT
        int j = 0;
        for (; j < full_iters - (NSLOT - 1); ++j) STEP(j, 6);
        STEP(j, 4); ++j;    // counted drain: 2 pairs left in flight
        STEP(j, 2); ++j;    // 1 pair left
        STEP(j, 0);         // drained
    }
    // Tail (plain loads; covers remainders and tiny shapes).
    for (int i = base + full_iters * CHUNK; i < n4; i += CHUNK) {
        int4 pv = preds[i];
        int4 tv = targs[i];
        process_vec(pv, tv, hist_cp);
    }
#undef STEP
    __syncthreads();

    // Marginals (NCOPY=32): wave w handles classes w, w+8, ... <NB.
    //  pc[c] = 640 contiguous words at c*640 (all t, all copies)
    //  tc[c] = for p in 0..19: 32 words at (p*20+c)*32 (bank = copy: clean)
    //  ic[c] = 32 words at (c*21)*32
    unsigned* dst = &partials[(size_t)blockIdx.x * PSTRIDE];
    for (int c = wid; c < NB; c += (BLK / 64)) {
        unsigned pcs = 0;
        #pragma unroll
        for (int k = 0; k < 640; k += 64) pcs += s_hist[c * 640 + k + lane];

        unsigned tcs = 0;
        {
            const int copy = lane & 31;
            const int p0   = lane >> 5;   // 0 or 1
            #pragma unroll
            for (int p = 0; p < NB; p += 2)
                tcs += s_hist[((p + p0) * NB + c) * NCOPY + copy];
        }
        unsigned ics = (lane < NCOPY) ? s_hist[(c * 21) * NCOPY + lane] : 0u;

        #pragma unroll
        for (int off = 32; off > 0; off >>= 1) {
            pcs += __shfl_xor(pcs, off);
            tcs += __shfl_xor(tcs, off);
            ics += __shfl_xor(ics, off);
        }
        if (lane == 0) {
            dst[c]          = pcs;
            dst[NB + c]     = tcs;
            dst[2 * NB + c] = ics;
        }
    }
}

// One block, 1024 threads. partials = nblocks rows x 16 int4 (coalesced).
__global__ __launch_bounds__(1024) void miou_reduce_kernel(
        const unsigned* __restrict__ partials, int nblocks,
        const int* __restrict__ nb_ptr, const int* __restrict__ smooth_ptr,
        float* __restrict__ out) {
    __shared__ unsigned s_tot[PSTRIDE];
    if (threadIdx.x < PSTRIDE) s_tot[threadIdx.x] = 0u;
    __syncthreads();

    const int col4 = threadIdx.x & 15;
    const int seg  = threadIdx.x >> 4;
    const int4* p4 = (const int4*)partials;

    unsigned ax = 0, ay = 0, az = 0, aw = 0;
    #pragma unroll 8
    for (int r = seg; r < nblocks; r += 64) {
        int4 v = p4[r * 16 + col4];
        ax += (unsigned)v.x; ay += (unsigned)v.y;
        az += (unsigned)v.z; aw += (unsigned)v.w;
    }
    atomicAdd(&s_tot[col4 * 4 + 0], ax);
    atomicAdd(&s_tot[col4 * 4 + 1], ay);
    atomicAdd(&s_tot[col4 * 4 + 2], az);
    atomicAdd(&s_tot[col4 * 4 + 3], aw);
    __syncthreads();

    if (threadIdx.x == 0) {
        const int   nb = *nb_ptr;
        const float s  = (float)(*smooth_ptr);
        float acc_iou = 0.0f;
        for (int c = 0; c < nb && c < NB; ++c) {
            float pc    = (float)s_tot[c];
            float tc    = (float)s_tot[NB + c];
            float inter = (float)s_tot[2 * NB + c];
            float uni   = pc + tc - inter;
            acc_iou += (inter + s) / (uni + s);
        }
        out[0] = 1.0f - acc_iou / (float)nb;
    }
}

extern "C" void kernel_launch(void* const* d_in, const int* in_sizes, int n_in,
                              void* d_out, int out_size, void* d_ws, size_t ws_size,
                              hipStream_t stream) {
    const int4* preds      = (const int4*)d_in[0];
    const int4* targs      = (const int4*)d_in[1];
    const int*  nb_ptr     = (const int*)d_in[2];
    const int*  smooth_ptr = (const int*)d_in[3];
    float*      out        = (float*)d_out;

    int n  = in_sizes[0];
    int n4 = n >> 2;  // 16M pixels, divisible by 4

    unsigned* partials = (unsigned*)d_ws;

    int grid = GRID_H;
    int max_grid = (n4 + BLK - 1) / BLK;
    if (grid > max_grid) grid = max_grid;
    size_t need_per_block = PSTRIDE * sizeof(unsigned);
    if ((size_t)grid * need_per_block > ws_size)
        grid = (int)(ws_size / need_per_block);

    int chunk = grid * BLK;
    int full  = (chunk > 0) ? (n4 / chunk) : 0;
    if (full < NSLOT) full = 0;   // tiny shapes -> tail path handles all

    miou_hist_kernel<<<grid, BLK, 0, stream>>>(preds, targs, partials, n4, full);
    miou_reduce_kernel<<<1, 1024, 0, stream>>>(partials, grid, nb_ptr, smooth_ptr, out);
}